// Round 7
// baseline (119.866 us; speedup 1.0000x reference)
//
#include <hip/hip_runtime.h>

// LengthRegulator, round 7: A/B on nontemporal stores.
// Structure = R3's measured-best gather (4096x256, two-half grid-stride) with
// REGULAR stores (the 6.9 TB/s harness fills use regular stores), plus the
// cheap shuffle-scan prep from R5/R6.
//   out[b,p,:] = x[b, searchsorted_right(cumsum(dur[b]), p), :]  (0 when p >= mel_len[b])
//   mel_len written as float at d_out + B*MAXLEN*C.
// B=32, T=1024, C=384, MAX_LEN=8192. Durations arrive as int32.

#define BB 32
#define TT 1024
#define CC 384
#define MAXLEN 8192
#define OUT0 (BB * MAXLEN * CC)   // 100663296 floats
#define QPR (CC / 4)              // 96 float4 per row

typedef float f32x4 __attribute__((ext_vector_type(4)));

// ---------------- Kernel 1: prep (one block per batch) ----------------
// int4 load + serial 4-sum + 64-lane shfl scan + cross-wave fixup (2 barriers),
// then each thread binary-searches 32 positions; coalesced idx writes.
__global__ __launch_bounds__(256) void lr_prep(const int4* __restrict__ dur4,
                                               int* __restrict__ idx,
                                               float* __restrict__ mel_out) {
    __shared__ int cum[TT];
    __shared__ int wsum[4];
    const int b = blockIdx.x, t = threadIdx.x, lane = t & 63, w = t >> 6;

    int4 d = dur4[b * (TT / 4) + t];
    int s0 = d.x, s1 = s0 + d.y, s2 = s1 + d.z, s3 = s2 + d.w;
    int v = s3;
    #pragma unroll
    for (int dd = 1; dd < 64; dd <<= 1) {
        int u = __shfl_up(v, dd);
        if (lane >= dd) v += u;
    }
    if (lane == 63) wsum[w] = v;
    __syncthreads();
    int prefix = 0;
    #pragma unroll
    for (int i = 0; i < 4; ++i) prefix += (i < w) ? wsum[i] : 0;
    const int base = prefix + v - s3;          // exclusive prefix for this thread's 4
    cum[4 * t + 0] = base + s0;
    cum[4 * t + 1] = base + s1;
    cum[4 * t + 2] = base + s2;
    cum[4 * t + 3] = base + s3;
    __syncthreads();
    const int ml = cum[TT - 1];
    if (t == 0) mel_out[b] = (float)ml;

    #pragma unroll
    for (int k = 0; k < MAXLEN / 256; ++k) {   // 32 positions per thread
        int p = t + k * 256;
        int r = -1;
        if (p < ml) {
            int lo = 0, hi = TT;
            while (lo < hi) {                  // lo = count(cum <= p)
                int mid = (lo + hi) >> 1;
                if (cum[mid] <= p) lo = mid + 1; else hi = mid;
            }
            r = (lo < TT - 1) ? lo : (TT - 1);
        }
        idx[b * MAXLEN + p] = r;
    }
}

// ---------------- Kernel 2: gather (R3 geometry, regular stores) ----------------
__global__ void lr_gather(const f32x4* __restrict__ x4,
                          const int* __restrict__ idx,
                          f32x4* __restrict__ out4) {
    const unsigned HALF = (unsigned)BB * MAXLEN * QPR / 2;  // 12582912
    const unsigned stride = gridDim.x * blockDim.x;         // runtime, as in R3
    for (unsigned q = blockIdx.x * blockDim.x + threadIdx.x; q < HALF; q += stride) {
        const unsigned q2 = q + HALF;
        unsigned row1 = q / QPR,  ln1 = q  - row1 * QPR;    // magic-mul, exact
        unsigned row2 = q2 / QPR, ln2 = q2 - row2 * QPR;
        int i1 = idx[row1];
        int i2 = idx[row2];
        f32x4 v1 = (f32x4)0.f, v2 = (f32x4)0.f;
        if (i1 >= 0) v1 = x4[((size_t)(row1 >> 13) * TT + (unsigned)i1) * QPR + ln1];
        if (i2 >= 0) v2 = x4[((size_t)(row2 >> 13) * TT + (unsigned)i2) * QPR + ln2];
        out4[q]  = v1;   // regular store (A/B vs __builtin_nontemporal_store)
        out4[q2] = v2;
    }
}

extern "C" void kernel_launch(void* const* d_in, const int* in_sizes, int n_in,
                              void* d_out, int out_size, void* d_ws, size_t ws_size,
                              hipStream_t stream) {
    const float* x   = (const float*)d_in[0];
    const int*   dur = (const int*)d_in[1];   // int64 in reference -> int32 on device
    float* out = (float*)d_out;

    int* idx = (int*)d_ws;                    // B*MAXLEN int32 = 1 MB

    lr_prep<<<BB, 256, 0, stream>>>((const int4*)dur, idx, out + OUT0);
    lr_gather<<<4096, 256, 0, stream>>>((const f32x4*)x, idx, (f32x4*)out);
}

// Round 8
// 90.367 us; speedup vs baseline: 1.3264x; 1.3264x over previous
//
#include <hip/hip_runtime.h>

// LengthRegulator, round 8: cheap shuffle-scan prep + EXACT R3 gather
// (4096x256, two-half runtime grid-stride, __builtin_nontemporal_store).
// R7 proved NT stores are worth ~30us (regular stores thrash L2 with the
// 402 MB write stream). R3's gather geometry was the measured best.
//   out[b,p,:] = x[b, searchsorted_right(cumsum(dur[b]), p), :]  (0 when p >= mel_len[b])
//   mel_len written as float at d_out + B*MAXLEN*C.
// B=32, T=1024, C=384, MAX_LEN=8192. Durations arrive as int32.

#define BB 32
#define TT 1024
#define CC 384
#define MAXLEN 8192
#define OUT0 (BB * MAXLEN * CC)   // 100663296 floats
#define QPR (CC / 4)              // 96 float4 per row

typedef float f32x4 __attribute__((ext_vector_type(4)));

// ---------------- Kernel 1: prep (one block per batch) ----------------
// int4 load + serial 4-sum + 64-lane shfl scan + cross-wave fixup (2 barriers),
// then each thread binary-searches 32 positions; coalesced idx writes.
__global__ __launch_bounds__(256) void lr_prep(const int4* __restrict__ dur4,
                                               int* __restrict__ idx,
                                               float* __restrict__ mel_out) {
    __shared__ int cum[TT];
    __shared__ int wsum[4];
    const int b = blockIdx.x, t = threadIdx.x, lane = t & 63, w = t >> 6;

    int4 d = dur4[b * (TT / 4) + t];
    int s0 = d.x, s1 = s0 + d.y, s2 = s1 + d.z, s3 = s2 + d.w;
    int v = s3;
    #pragma unroll
    for (int dd = 1; dd < 64; dd <<= 1) {
        int u = __shfl_up(v, dd);
        if (lane >= dd) v += u;
    }
    if (lane == 63) wsum[w] = v;
    __syncthreads();
    int prefix = 0;
    #pragma unroll
    for (int i = 0; i < 4; ++i) prefix += (i < w) ? wsum[i] : 0;
    const int base = prefix + v - s3;          // exclusive prefix for this thread's 4
    cum[4 * t + 0] = base + s0;
    cum[4 * t + 1] = base + s1;
    cum[4 * t + 2] = base + s2;
    cum[4 * t + 3] = base + s3;
    __syncthreads();
    const int ml = cum[TT - 1];
    if (t == 0) mel_out[b] = (float)ml;

    #pragma unroll
    for (int k = 0; k < MAXLEN / 256; ++k) {   // 32 positions per thread
        int p = t + k * 256;
        int r = -1;
        if (p < ml) {
            int lo = 0, hi = TT;
            while (lo < hi) {                  // lo = count(cum <= p)
                int mid = (lo + hi) >> 1;
                if (cum[mid] <= p) lo = mid + 1; else hi = mid;
            }
            r = (lo < TT - 1) ? lo : (TT - 1);
        }
        idx[b * MAXLEN + p] = r;
    }
}

// ---------------- Kernel 2: gather (R3 exact: NT stores, runtime stride) ----------------
__global__ void lr_gather(const f32x4* __restrict__ x4,
                          const int* __restrict__ idx,
                          f32x4* __restrict__ out4) {
    const unsigned HALF = (unsigned)BB * MAXLEN * QPR / 2;  // 12582912
    const unsigned stride = gridDim.x * blockDim.x;
    for (unsigned q = blockIdx.x * blockDim.x + threadIdx.x; q < HALF; q += stride) {
        const unsigned q2 = q + HALF;
        unsigned row1 = q / QPR,  ln1 = q  - row1 * QPR;    // magic-mul, exact
        unsigned row2 = q2 / QPR, ln2 = q2 - row2 * QPR;
        int i1 = idx[row1];
        int i2 = idx[row2];
        f32x4 v1 = (f32x4)0.f, v2 = (f32x4)0.f;
        if (i1 >= 0) v1 = x4[((size_t)(row1 >> 13) * TT + (unsigned)i1) * QPR + ln1];
        if (i2 >= 0) v2 = x4[((size_t)(row2 >> 13) * TT + (unsigned)i2) * QPR + ln2];
        __builtin_nontemporal_store(v1, &out4[q]);
        __builtin_nontemporal_store(v2, &out4[q2]);
    }
}

extern "C" void kernel_launch(void* const* d_in, const int* in_sizes, int n_in,
                              void* d_out, int out_size, void* d_ws, size_t ws_size,
                              hipStream_t stream) {
    const float* x   = (const float*)d_in[0];
    const int*   dur = (const int*)d_in[1];   // int64 in reference -> int32 on device
    float* out = (float*)d_out;

    int* idx = (int*)d_ws;                    // B*MAXLEN int32 = 1 MB

    lr_prep<<<BB, 256, 0, stream>>>((const int4*)dur, idx, out + OUT0);
    lr_gather<<<4096, 256, 0, stream>>>((const f32x4*)x, idx, (f32x4*)out);
}